// Round 17
// baseline (165.634 us; speedup 1.0000x reference)
//
#include <hip/hip_runtime.h>
#include <hip/hip_bf16.h>
#include <math.h>

// Problem constants (B,C,L,H fixed by setup_inputs)
#define NB 8
#define NC 512
#define NL 8192
#define NH 128
#define FEPS 1e-5f
#define NKEEP 358   // int(512*0.7)

typedef __attribute__((ext_vector_type(8))) short short8;
typedef __attribute__((ext_vector_type(4))) float f32x4;

__device__ __forceinline__ unsigned short f2bf(float x) {
  unsigned u = __float_as_uint(x);
  return (unsigned short)((u + 0x7fffu + ((u >> 16) & 1u)) >> 16);  // RNE
}
__device__ __forceinline__ unsigned pack2(float a, float b) {
  return (unsigned)f2bf(a) | ((unsigned)f2bf(b) << 16);
}

// ---------------- K0: convert gate weights to bf16, zero accumulators ----------------
__global__ __launch_bounds__(256) void k0_prep(
    const float* __restrict__ gw1, const float* __restrict__ gw2,
    unsigned short* __restrict__ gw1b, unsigned short* __restrict__ gw2b,
    float* __restrict__ csum, float* __restrict__ gsum) {
  int i = blockIdx.x * 256 + threadIdx.x;   // 256*256 = 65536 = H*C = C*H
  gw1b[i] = f2bf(gw1[i]);
  gw2b[i] = f2bf(gw2[i]);
  if (i < NB * NC) { csum[i] = 0.f; gsum[i] = 0.f; }
}

// ---------------- K12: gate blocks (0..511) + x-stream blocks (512..4607) ----------------
// R11/R15 measured-best form, verbatim. Gate path = R7 schedule + low-LDS layout (38.9KB:
// Hts/gsum_s alias the dead A-dbuf; biases direct from L2). x path uses CACHED float4
// loads -> x stays L3-resident for k4.
__global__ __launch_bounds__(256, 2) void k12_gate_x(
    const float* __restrict__ cin, const float* __restrict__ x,
    const unsigned short* __restrict__ gw1b, const unsigned short* __restrict__ gw2b,
    const float* __restrict__ gb1, const float* __restrict__ gb2,
    float* __restrict__ gsum_g, float* __restrict__ csum_g,
    float* __restrict__ xsum, float* __restrict__ xsumsq) {
  __shared__ __align__(16) unsigned AsU[2 * 128 * 36];   // 36864B: A dbuf / Hts+gsum_s alias / GEMM2 B dbuf
  __shared__ float csum_s[NC];                           // 2048B  -> ~38.9KB total

  const int t = threadIdx.x;

  // ================= x-stats path (blocks 512..4607): near-roofline streamer =================
  if (blockIdx.x >= 512) {
    const int bc = blockIdx.x - 512;          // 0..NB*NC-1
    const float4* xp = reinterpret_cast<const float4*>(x + (size_t)bc * NL);
    float s1 = 0.f, s2 = 0.f;
#pragma unroll
    for (int i = 0; i < 8; ++i) {
      float4 v = xp[i * 256 + t];
      s1 += v.x + v.y + v.z + v.w;
      s2 += v.x * v.x + v.y * v.y + v.z * v.z + v.w * v.w;
    }
    for (int off = 32; off; off >>= 1) { s1 += __shfl_down(s1, off); s2 += __shfl_down(s2, off); }
    float* red = reinterpret_cast<float*>(AsU);
    if ((t & 63) == 0) { red[t >> 6] = s1; red[4 + (t >> 6)] = s2; }
    __syncthreads();
    if (t == 0) {
      xsum[bc]   = red[0] + red[1] + red[2] + red[3];
      xsumsq[bc] = red[4] + red[5] + red[6] + red[7];
    }
    return;
  }

  // ================= gate path (blocks 0..511): R7 schedule, low-LDS layout =================
  const int lane = t & 63;
  const int w = t >> 6;
  const int r = lane & 15;
  const int kg = lane >> 4;
  const int b = blockIdx.x >> 6;
  const int l0 = (blockIdx.x & 63) * 128;

  // staging roles (A): p = chpair 0..31, q = quad-in-pass
  const int p = t >> 3;
  const int q = t & 7;

  f32x4 acc0[8], acc1[8];
#pragma unroll
  for (int i = 0; i < 8; ++i) { acc0[i] = (f32x4){0.f,0.f,0.f,0.f}; acc1[i] = (f32x4){0.f,0.f,0.f,0.f}; }

  const float* cbase = cin + (size_t)b * NC * NL + l0;
  const unsigned short* gw1r = gw1b + (size_t)r * NC + kg * 8;   // + ht*16*NC + k*64 + kk*32

  // two named staging register sets: A holds even chunks, B holds odd chunks (rule-#20 static)
  f32x4 vaA[4], vbA[4], vaB[4], vbB[4];

#define LOADA(dA, dB, kch) { \
    _Pragma("unroll") \
    for (int pass = 0; pass < 4; ++pass) { \
      const float* cp0 = cbase + (size_t)((kch) * 64 + 2 * p) * NL + 32 * pass + 4 * q; \
      dA[pass] = __builtin_nontemporal_load(reinterpret_cast<const f32x4*>(cp0)); \
      dB[pass] = __builtin_nontemporal_load(reinterpret_cast<const f32x4*>(cp0 + NL)); \
    } }

#define WRITEA(sA, sB, kch, bufi) { \
    unsigned* dst = AsU + (bufi) * (128 * 36); \
    float sa = 0.f, sb = 0.f; \
    _Pragma("unroll") \
    for (int pass = 0; pass < 4; ++pass) { \
      const int ll = 32 * pass + 4 * q; \
      sa += sA[pass].x + sA[pass].y + sA[pass].z + sA[pass].w; \
      sb += sB[pass].x + sB[pass].y + sB[pass].z + sB[pass].w; \
      dst[(ll + 0) * 36 + p] = pack2(sA[pass].x, sB[pass].x); \
      dst[(ll + 1) * 36 + p] = pack2(sA[pass].y, sB[pass].y); \
      dst[(ll + 2) * 36 + p] = pack2(sA[pass].z, sB[pass].z); \
      dst[(ll + 3) * 36 + p] = pack2(sA[pass].w, sB[pass].w); \
    } \
    sa += __shfl_xor(sa, 1); sa += __shfl_xor(sa, 2); sa += __shfl_xor(sa, 4); \
    sb += __shfl_xor(sb, 1); sb += __shfl_xor(sb, 2); sb += __shfl_xor(sb, 4); \
    if ((lane & 7) == 0) { \
      atomicAdd(&csum_s[(kch) * 64 + 2 * p],     sa); \
      atomicAdd(&csum_s[(kch) * 64 + 2 * p + 1], sb); \
    } }

  // prologue: chunks 0 and 1 in flight, init csum, full drain ONCE, stage chunk 0
  LOADA(vaA, vbA, 0)
  LOADA(vaB, vbB, 1)
  for (int i = t; i < NC; i += 256) csum_s[i] = 0.f;
  __syncthreads();                      // one-time vmcnt drain, outside the hot loop
  WRITEA(vaA, vbA, 0, 0)
  asm volatile("s_waitcnt lgkmcnt(0)" ::: "memory");
  __builtin_amdgcn_s_barrier();
  __builtin_amdgcn_sched_barrier(0);

  // ---------------- GEMM1 main loop: raw barrier, prefetch never drained (R7-verified) ----------------
  for (int k = 0; k < 8; ++k) {
    const unsigned* Abuf = AsU + (k & 1) * (128 * 36);
    // 1) all B-frags for this chunk (L2), BEFORE the deep prefetch
    short8 bfr[16];
#pragma unroll
    for (int ht = 0; ht < 8; ++ht) {
      bfr[2 * ht]     = *reinterpret_cast<const short8*>(gw1r + (size_t)(ht * 16) * NC + k * 64);
      bfr[2 * ht + 1] = *reinterpret_cast<const short8*>(gw1r + (size_t)(ht * 16) * NC + k * 64 + 32);
    }
    // 2) A-frags from LDS (written iter k-1, visible via barrier)
    short8 a0[2], a1[2];
#pragma unroll
    for (int kk = 0; kk < 2; ++kk) {
      a0[kk] = *reinterpret_cast<const short8*>(&Abuf[(32 * w + r)      * 36 + 16 * kk + 4 * kg]);
      a1[kk] = *reinterpret_cast<const short8*>(&Abuf[(32 * w + 16 + r) * 36 + 16 * kk + 4 * kg]);
    }
    __builtin_amdgcn_sched_barrier(0);
    // 3) stage chunk k+1 (counted vmcnt; loads had a full iteration of flight)
    if (k < 7) {
      if ((k & 1) == 0) { WRITEA(vaB, vbB, k + 1, 1) } else { WRITEA(vaA, vbA, k + 1, 0) }
    }
    __builtin_amdgcn_sched_barrier(0);
    // 4) deep prefetch chunk k+2 into the freed set — youngest VMEM
    if (k < 6) {
      if ((k & 1) == 0) { LOADA(vaA, vbA, k + 2) } else { LOADA(vaB, vbB, k + 2) }
    }
    __builtin_amdgcn_sched_barrier(0);
    // 5) MFMA: waits cover bfr + a-frags only
#pragma unroll
    for (int kk = 0; kk < 2; ++kk) {
#pragma unroll
      for (int ht = 0; ht < 8; ++ht) {
        acc0[ht] = __builtin_amdgcn_mfma_f32_16x16x32_bf16(a0[kk], bfr[2 * ht + kk], acc0[ht], 0, 0, 0);
        acc1[ht] = __builtin_amdgcn_mfma_f32_16x16x32_bf16(a1[kk], bfr[2 * ht + kk], acc1[ht], 0, 0, 0);
      }
    }
    // 6) publish my DS ops, raw barrier — NO vmcnt drain
    __builtin_amdgcn_sched_barrier(0);
    asm volatile("s_waitcnt lgkmcnt(0)" ::: "memory");
    __builtin_amdgcn_s_barrier();
    __builtin_amdgcn_sched_barrier(0);
  }

  // ---------------- epilogue: bias+relu -> Hts (ALIASES dead A-dbuf) ----------------
  // D map: col=lane&15, row=(lane>>4)*4+reg. AsU fully dead after GEMM1's final barrier.
  unsigned short (*Hts)[32][136] = reinterpret_cast<unsigned short (*)[32][136]>(AsU);
#pragma unroll
  for (int ht = 0; ht < 8; ++ht) {
    const float bias = gb1[16 * ht + r];                 // direct from L2 (epilogue, once)
#pragma unroll
    for (int reg = 0; reg < 4; ++reg) {
      Hts[w][4 * kg + reg][16 * ht + r]      = f2bf(fmaxf(acc0[ht][reg] + bias, 0.f));
      Hts[w][16 + 4 * kg + reg][16 * ht + r] = f2bf(fmaxf(acc1[ht][reg] + bias, 0.f));
    }
  }
  // wave-local write->read: per-wave DS ordering, no barrier needed
  short8 af0[4], af1[4];
#pragma unroll
  for (int kk = 0; kk < 4; ++kk) {
    af0[kk] = *reinterpret_cast<const short8*>(&Hts[w][r][32 * kk + 8 * kg]);
    af1[kk] = *reinterpret_cast<const short8*>(&Hts[w][16 + r][32 * kk + 8 * kg]);
  }
  // gsum_s aliases AsU bytes 34816..36864 (disjoint from Hts 0..34816 and B-dbuf 0..32768)
  float* gsum_s = reinterpret_cast<float*>(reinterpret_cast<char*>(AsU) + 34816);
  for (int i = t; i < NC; i += 256) gsum_s[i] = 0.f;
  // barrier: all af reads + gsum init retired before anyone writes the B-dbuf over Hts
  asm volatile("s_waitcnt lgkmcnt(0)" ::: "memory");
  __builtin_amdgcn_s_barrier();

  // ---------------- GEMM2: gsum[c] += sigmoid(H^T . gw2[c] + gb2), B dbuf in AsU ----------------
  unsigned short* Bs2 = reinterpret_cast<unsigned short*>(AsU);
  const int crow = lane >> 4;    // B2: row offset 0..3
  const int bs2  = lane & 15;    // B2: slot 0..15
  short8 bv[4];

#define LOADB2(ccn) { \
    _Pragma("unroll") \
    for (int j = 0; j < 4; ++j) { \
      const int cl = 16 * w + 4 * j + crow; \
      bv[j] = *reinterpret_cast<const short8*>(gw2b + (size_t)((ccn) * 64 + cl) * NH + bs2 * 8); \
    } }
#define WRITEB2(ccn) { \
    unsigned short* dstb = Bs2 + ((ccn) & 1) * 8192; \
    _Pragma("unroll") \
    for (int j = 0; j < 4; ++j) { \
      const int cl = 16 * w + 4 * j + crow; \
      *reinterpret_cast<short8*>(&dstb[cl * 128 + ((bs2 ^ (cl & 7)) * 8)]) = bv[j]; \
    } }

  LOADB2(0)
  WRITEB2(0)                      // safe: behind the af-protection barrier
  __syncthreads();
  for (int cc = 0; cc < 8; ++cc) {
    // bias loads FIRST (older than the LOADB2 prefetch -> waits never drain it)
    float gb2v[4];
#pragma unroll
    for (int ctt = 0; ctt < 4; ++ctt) gb2v[ctt] = gb2[cc * 64 + 16 * ctt + r];
    if (cc < 7) LOADB2(cc + 1)
    const unsigned short* Bbuf = Bs2 + (cc & 1) * 8192;
#pragma unroll
    for (int ctt = 0; ctt < 4; ++ctt) {
      f32x4 z0 = (f32x4){0.f,0.f,0.f,0.f}, z1 = (f32x4){0.f,0.f,0.f,0.f};
#pragma unroll
      for (int kk = 0; kk < 4; ++kk) {
        const short8 bf = *reinterpret_cast<const short8*>(
            &Bbuf[(16 * ctt + r) * 128 + (((4 * kk + kg) ^ (r & 7)) * 8)]);
        z0 = __builtin_amdgcn_mfma_f32_16x16x32_bf16(af0[kk], bf, z0, 0, 0, 0);
        z1 = __builtin_amdgcn_mfma_f32_16x16x32_bf16(af1[kk], bf, z1, 0, 0, 0);
      }
      const float bias = gb2v[ctt];
      float s = 0.f;
#pragma unroll
      for (int reg = 0; reg < 4; ++reg) {
        s += 1.f / (1.f + __expf(-(z0[reg] + bias)));
        s += 1.f / (1.f + __expf(-(z1[reg] + bias)));
      }
      s += __shfl_xor(s, 16);
      s += __shfl_xor(s, 32);
      if (lane < 16) atomicAdd(&gsum_s[cc * 64 + 16 * ctt + lane], s);
    }
    if (cc < 7) WRITEB2(cc + 1)
    __syncthreads();
  }
  for (int i = t; i < NC; i += 256) {
    atomicAdd(&gsum_g[b * NC + i], gsum_s[i]);
    atomicAdd(&csum_g[b * NC + i], csum_s[i]);
  }
}

// ---------------- K3: finalize stats + affine MLP; 1024 thr (was 256) for 4x GEMV parallelism ----------------
// Only 8 blocks run -> intra-block parallelism is the lever. FP-order preserving:
// MLP2 = 1 output/thread (same sequential 128-float4 dot); MLP1 untouched (t<128);
// stats/finalize restrided (per-c math identical; double-sum reorder < fp32 ulp).
__global__ __launch_bounds__(1024) void k3_final(
    const float* __restrict__ xsum, const float* __restrict__ xsumsq,
    const float* __restrict__ csum, const float* __restrict__ gsum,
    const float* __restrict__ mw1, const float* __restrict__ mb1,
    const float* __restrict__ mw2, const float* __restrict__ mb2,
    float* __restrict__ a_arr, float* __restrict__ d_arr) {
  __shared__ __align__(16) float cp[NC];
  __shared__ __align__(16) float hm[NH];
  __shared__ float gbv[2 * NC];
  __shared__ double red[32];
  __shared__ float mu_l_s, sig_l_s;
  const int b = blockIdx.x, t = threadIdx.x;

  double s1 = 0.0, s2 = 0.0;
  for (int c = t; c < NC; c += 1024) { s1 += (double)xsum[b * NC + c]; s2 += (double)xsumsq[b * NC + c]; }
  for (int off = 32; off; off >>= 1) { s1 += __shfl_down(s1, off); s2 += __shfl_down(s2, off); }
  if ((t & 63) == 0) { red[(t >> 6) * 2] = s1; red[(t >> 6) * 2 + 1] = s2; }
  for (int c = t; c < NC; c += 1024) cp[c] = csum[b * NC + c] * (1.f / NL);
  __syncthreads();
  if (t == 0) {
    double S1 = 0.0, S2 = 0.0;
#pragma unroll
    for (int i = 0; i < 16; ++i) { S1 += red[2 * i]; S2 += red[2 * i + 1]; }
    double n = (double)NC * NL;
    double mu = S1 / n;
    double var = S2 / n - mu * mu;
    mu_l_s = (float)mu;
    sig_l_s = (float)sqrt(var + (double)FEPS);
  }
  __syncthreads();
  if (t < NH) {
    const float4* row = reinterpret_cast<const float4*>(mw1 + (size_t)t * NC);
    const float4* cpv = reinterpret_cast<const float4*>(cp);
    float acc = mb1[t];
    for (int i = 0; i < NC / 4; ++i) {
      float4 wv = row[i], xv = cpv[i];
      acc += wv.x * xv.x + wv.y * xv.y + wv.z * xv.z + wv.w * xv.w;
    }
    hm[t] = fmaxf(acc, 0.f);
  }
  __syncthreads();
  {
    const int o = t;                                   // 1024 threads = 2*NC outputs, 1 each
    const float4* row = reinterpret_cast<const float4*>(mw2 + (size_t)o * NH);
    const float4* hv = reinterpret_cast<const float4*>(hm);
    float acc = mb2[o];
    for (int i = 0; i < NH / 4; ++i) {
      float4 wv = row[i], xv = hv[i];
      acc += wv.x * xv.x + wv.y * xv.y + wv.z * xv.z + wv.w * xv.w;
    }
    gbv[o] = acc;
  }
  __syncthreads();
  const float mu_l = mu_l_s, sig_l = sig_l_s;
  for (int c = t; c < NC; c += 1024) {
    float gm = gsum[b * NC + c] * (1.f / NL);
    double mu_c = (double)xsum[b * NC + c] / NL;
    double var_c = (double)xsumsq[b * NC + c] / NL - mu_c * mu_c;
    float sig_c = (float)sqrt(var_c + (double)FEPS);
    float mu = gm * (float)mu_c + (1.f - gm) * mu_l;
    float sg = gm * sig_c + (1.f - gm) * sig_l;
    float gamma = gbv[c], beta = gbv[NC + c];
    float A = (1.f + gamma) / sg;
    a_arr[b * NC + c] = A;
    d_arr[b * NC + c] = beta - A * mu;
  }
}

// ---------------- K4: y = A*x + D, CACHED x reads (L3-warm from k12), nt y stores, imp = sum |y| ----------------
__global__ __launch_bounds__(256) void k4_y(
    const float* __restrict__ x, const float* __restrict__ a_arr,
    const float* __restrict__ d_arr, float* __restrict__ out, float* __restrict__ imp) {
  const int bc = blockIdx.x, t = threadIdx.x;
  const float A = a_arr[bc], D = d_arr[bc];
  const f32x4* xp = reinterpret_cast<const f32x4*>(x + (size_t)bc * NL);
  f32x4* op = reinterpret_cast<f32x4*>(out + (size_t)bc * NL);
  float s = 0.f;
#pragma unroll
  for (int i = 0; i < 8; ++i) {
    f32x4 v = xp[i * 256 + t];            // CACHED: x is L3-resident from k12's x-path
    f32x4 y;
    y.x = fmaf(A, v.x, D); y.y = fmaf(A, v.y, D);
    y.z = fmaf(A, v.z, D); y.w = fmaf(A, v.w, D);
    s += fabsf(y.x) + fabsf(y.y) + fabsf(y.z) + fabsf(y.w);
    __builtin_nontemporal_store(y, op + i * 256 + t);         // out never re-read
  }
  for (int off = 32; off; off >>= 1) s += __shfl_down(s, off);
  __shared__ float rs[4];
  if ((t & 63) == 0) rs[t >> 6] = s;
  __syncthreads();
  if (t == 0) imp[bc] = rs[0] + rs[1] + rs[2] + rs[3];
}

// ---------------- K5: fused top-k rank (jax.lax.top_k tie semantics) + zero dropped rows ----------------
__global__ __launch_bounds__(256) void k5_apply(
    const float* __restrict__ imp, float* __restrict__ out) {
  const int bc = blockIdx.x;
  const int b = bc >> 9;            // NC = 512
  const int c = bc & (NC - 1);
  const int t = threadIdx.x;
  const float* row = imp + b * NC;
  const float mine = row[c];
  int cnt = 0;
#pragma unroll
  for (int jj = 0; jj < 2; ++jj) {
    const int j = jj * 256 + t;
    const float o = row[j];
    cnt += (o > mine) || (o == mine && j < c);
  }
  for (int off = 32; off; off >>= 1) cnt += __shfl_down(cnt, off);
  __shared__ int rs[4];
  if ((t & 63) == 0) rs[t >> 6] = cnt;
  __syncthreads();
  const int rank = rs[0] + rs[1] + rs[2] + rs[3];   // block-uniform
  if (rank < NKEEP) return;
  f32x4* op = reinterpret_cast<f32x4*>(out + (size_t)bc * NL);
  const f32x4 z = (f32x4){0.f, 0.f, 0.f, 0.f};
#pragma unroll
  for (int i = 0; i < 8; ++i) __builtin_nontemporal_store(z, op + i * 256 + t);
}

extern "C" void kernel_launch(void* const* d_in, const int* in_sizes, int n_in,
                              void* d_out, int out_size, void* d_ws, size_t ws_size,
                              hipStream_t stream) {
  const float* x   = (const float*)d_in[0];
  const float* c   = (const float*)d_in[1];
  const float* gw1 = (const float*)d_in[2];
  const float* gb1 = (const float*)d_in[3];
  const float* gw2 = (const float*)d_in[4];
  const float* gb2 = (const float*)d_in[5];
  const float* mw1 = (const float*)d_in[6];
  const float* mb1 = (const float*)d_in[7];
  const float* mw2 = (const float*)d_in[8];
  const float* mb2 = (const float*)d_in[9];
  float* out = (float*)d_out;
  char* ws = (char*)d_ws;

  unsigned short* gw1b = (unsigned short*)(ws);             // 131072 B
  unsigned short* gw2b = (unsigned short*)(ws + 131072);    // 131072 B
  float* xsum   = (float*)(ws + 262144);
  float* xsumsq = (float*)(ws + 278528);
  float* csum   = (float*)(ws + 294912);
  float* gsum   = (float*)(ws + 311296);
  float* a_arr  = (float*)(ws + 327680);
  float* d_arr  = (float*)(ws + 344064);
  float* imp    = (float*)(ws + 360448);

  k0_prep<<<256, 256, 0, stream>>>(gw1, gw2, gw1b, gw2b, csum, gsum);
  k12_gate_x<<<512 + NB * NC, 256, 0, stream>>>(c, x, gw1b, gw2b, gb1, gb2,
                                                gsum, csum, xsum, xsumsq);
  k3_final<<<NB, 1024, 0, stream>>>(xsum, xsumsq, csum, gsum, mw1, mb1, mw2, mb2, a_arr, d_arr);
  k4_y<<<NB * NC, 256, 0, stream>>>(x, a_arr, d_arr, out, imp);
  k5_apply<<<NB * NC, 256, 0, stream>>>(imp, out);
}

// Round 18
// 162.751 us; speedup vs baseline: 1.0177x; 1.0177x over previous
//
#include <hip/hip_runtime.h>
#include <hip/hip_bf16.h>
#include <math.h>

// Problem constants (B,C,L,H fixed by setup_inputs)
#define NB 8
#define NC 512
#define NL 8192
#define NH 128
#define FEPS 1e-5f
#define NKEEP 358   // int(512*0.7)

typedef __attribute__((ext_vector_type(8))) short short8;
typedef __attribute__((ext_vector_type(4))) float f32x4;

__device__ __forceinline__ unsigned short f2bf(float x) {
  unsigned u = __float_as_uint(x);
  return (unsigned short)((u + 0x7fffu + ((u >> 16) & 1u)) >> 16);  // RNE
}
__device__ __forceinline__ unsigned pack2(float a, float b) {
  return (unsigned)f2bf(a) | ((unsigned)f2bf(b) << 16);
}

// ---------------- K0: convert gate weights to bf16, zero accumulators ----------------
__global__ __launch_bounds__(256) void k0_prep(
    const float* __restrict__ gw1, const float* __restrict__ gw2,
    unsigned short* __restrict__ gw1b, unsigned short* __restrict__ gw2b,
    float* __restrict__ csum, float* __restrict__ gsum) {
  int i = blockIdx.x * 256 + threadIdx.x;   // 256*256 = 65536 = H*C = C*H
  gw1b[i] = f2bf(gw1[i]);
  gw2b[i] = f2bf(gw2[i]);
  if (i < NB * NC) { csum[i] = 0.f; gsum[i] = 0.f; }
}

// ---------------- K12: gate blocks (0..511) + x-stream blocks (512..4607) ----------------
// R15 measured-best form (163.0us), verbatim. Gate path = R7 schedule + low-LDS layout
// (38.9KB: Hts/gsum_s alias the dead A-dbuf; biases direct from L2). x path uses CACHED
// float4 loads -> x stays L3-resident for k4.
__global__ __launch_bounds__(256, 2) void k12_gate_x(
    const float* __restrict__ cin, const float* __restrict__ x,
    const unsigned short* __restrict__ gw1b, const unsigned short* __restrict__ gw2b,
    const float* __restrict__ gb1, const float* __restrict__ gb2,
    float* __restrict__ gsum_g, float* __restrict__ csum_g,
    float* __restrict__ xsum, float* __restrict__ xsumsq) {
  __shared__ __align__(16) unsigned AsU[2 * 128 * 36];   // 36864B: A dbuf / Hts+gsum_s alias / GEMM2 B dbuf
  __shared__ float csum_s[NC];                           // 2048B  -> ~38.9KB total

  const int t = threadIdx.x;

  // ================= x-stats path (blocks 512..4607): near-roofline streamer =================
  if (blockIdx.x >= 512) {
    const int bc = blockIdx.x - 512;          // 0..NB*NC-1
    const float4* xp = reinterpret_cast<const float4*>(x + (size_t)bc * NL);
    float s1 = 0.f, s2 = 0.f;
#pragma unroll
    for (int i = 0; i < 8; ++i) {
      float4 v = xp[i * 256 + t];
      s1 += v.x + v.y + v.z + v.w;
      s2 += v.x * v.x + v.y * v.y + v.z * v.z + v.w * v.w;
    }
    for (int off = 32; off; off >>= 1) { s1 += __shfl_down(s1, off); s2 += __shfl_down(s2, off); }
    float* red = reinterpret_cast<float*>(AsU);
    if ((t & 63) == 0) { red[t >> 6] = s1; red[4 + (t >> 6)] = s2; }
    __syncthreads();
    if (t == 0) {
      xsum[bc]   = red[0] + red[1] + red[2] + red[3];
      xsumsq[bc] = red[4] + red[5] + red[6] + red[7];
    }
    return;
  }

  // ================= gate path (blocks 0..511): R7 schedule, low-LDS layout =================
  const int lane = t & 63;
  const int w = t >> 6;
  const int r = lane & 15;
  const int kg = lane >> 4;
  const int b = blockIdx.x >> 6;
  const int l0 = (blockIdx.x & 63) * 128;

  // staging roles (A): p = chpair 0..31, q = quad-in-pass
  const int p = t >> 3;
  const int q = t & 7;

  f32x4 acc0[8], acc1[8];
#pragma unroll
  for (int i = 0; i < 8; ++i) { acc0[i] = (f32x4){0.f,0.f,0.f,0.f}; acc1[i] = (f32x4){0.f,0.f,0.f,0.f}; }

  const float* cbase = cin + (size_t)b * NC * NL + l0;
  const unsigned short* gw1r = gw1b + (size_t)r * NC + kg * 8;   // + ht*16*NC + k*64 + kk*32

  // two named staging register sets: A holds even chunks, B holds odd chunks (rule-#20 static)
  f32x4 vaA[4], vbA[4], vaB[4], vbB[4];

#define LOADA(dA, dB, kch) { \
    _Pragma("unroll") \
    for (int pass = 0; pass < 4; ++pass) { \
      const float* cp0 = cbase + (size_t)((kch) * 64 + 2 * p) * NL + 32 * pass + 4 * q; \
      dA[pass] = __builtin_nontemporal_load(reinterpret_cast<const f32x4*>(cp0)); \
      dB[pass] = __builtin_nontemporal_load(reinterpret_cast<const f32x4*>(cp0 + NL)); \
    } }

#define WRITEA(sA, sB, kch, bufi) { \
    unsigned* dst = AsU + (bufi) * (128 * 36); \
    float sa = 0.f, sb = 0.f; \
    _Pragma("unroll") \
    for (int pass = 0; pass < 4; ++pass) { \
      const int ll = 32 * pass + 4 * q; \
      sa += sA[pass].x + sA[pass].y + sA[pass].z + sA[pass].w; \
      sb += sB[pass].x + sB[pass].y + sB[pass].z + sB[pass].w; \
      dst[(ll + 0) * 36 + p] = pack2(sA[pass].x, sB[pass].x); \
      dst[(ll + 1) * 36 + p] = pack2(sA[pass].y, sB[pass].y); \
      dst[(ll + 2) * 36 + p] = pack2(sA[pass].z, sB[pass].z); \
      dst[(ll + 3) * 36 + p] = pack2(sA[pass].w, sB[pass].w); \
    } \
    sa += __shfl_xor(sa, 1); sa += __shfl_xor(sa, 2); sa += __shfl_xor(sa, 4); \
    sb += __shfl_xor(sb, 1); sb += __shfl_xor(sb, 2); sb += __shfl_xor(sb, 4); \
    if ((lane & 7) == 0) { \
      atomicAdd(&csum_s[(kch) * 64 + 2 * p],     sa); \
      atomicAdd(&csum_s[(kch) * 64 + 2 * p + 1], sb); \
    } }

  // prologue: chunks 0 and 1 in flight, init csum, full drain ONCE, stage chunk 0
  LOADA(vaA, vbA, 0)
  LOADA(vaB, vbB, 1)
  for (int i = t; i < NC; i += 256) csum_s[i] = 0.f;
  __syncthreads();                      // one-time vmcnt drain, outside the hot loop
  WRITEA(vaA, vbA, 0, 0)
  asm volatile("s_waitcnt lgkmcnt(0)" ::: "memory");
  __builtin_amdgcn_s_barrier();
  __builtin_amdgcn_sched_barrier(0);

  // ---------------- GEMM1 main loop: raw barrier, prefetch never drained (R7-verified) ----------------
  for (int k = 0; k < 8; ++k) {
    const unsigned* Abuf = AsU + (k & 1) * (128 * 36);
    // 1) all B-frags for this chunk (L2), BEFORE the deep prefetch
    short8 bfr[16];
#pragma unroll
    for (int ht = 0; ht < 8; ++ht) {
      bfr[2 * ht]     = *reinterpret_cast<const short8*>(gw1r + (size_t)(ht * 16) * NC + k * 64);
      bfr[2 * ht + 1] = *reinterpret_cast<const short8*>(gw1r + (size_t)(ht * 16) * NC + k * 64 + 32);
    }
    // 2) A-frags from LDS (written iter k-1, visible via barrier)
    short8 a0[2], a1[2];
#pragma unroll
    for (int kk = 0; kk < 2; ++kk) {
      a0[kk] = *reinterpret_cast<const short8*>(&Abuf[(32 * w + r)      * 36 + 16 * kk + 4 * kg]);
      a1[kk] = *reinterpret_cast<const short8*>(&Abuf[(32 * w + 16 + r) * 36 + 16 * kk + 4 * kg]);
    }
    __builtin_amdgcn_sched_barrier(0);
    // 3) stage chunk k+1 (counted vmcnt; loads had a full iteration of flight)
    if (k < 7) {
      if ((k & 1) == 0) { WRITEA(vaB, vbB, k + 1, 1) } else { WRITEA(vaA, vbA, k + 1, 0) }
    }
    __builtin_amdgcn_sched_barrier(0);
    // 4) deep prefetch chunk k+2 into the freed set — youngest VMEM
    if (k < 6) {
      if ((k & 1) == 0) { LOADA(vaA, vbA, k + 2) } else { LOADA(vaB, vbB, k + 2) }
    }
    __builtin_amdgcn_sched_barrier(0);
    // 5) MFMA: waits cover bfr + a-frags only
#pragma unroll
    for (int kk = 0; kk < 2; ++kk) {
#pragma unroll
      for (int ht = 0; ht < 8; ++ht) {
        acc0[ht] = __builtin_amdgcn_mfma_f32_16x16x32_bf16(a0[kk], bfr[2 * ht + kk], acc0[ht], 0, 0, 0);
        acc1[ht] = __builtin_amdgcn_mfma_f32_16x16x32_bf16(a1[kk], bfr[2 * ht + kk], acc1[ht], 0, 0, 0);
      }
    }
    // 6) publish my DS ops, raw barrier — NO vmcnt drain
    __builtin_amdgcn_sched_barrier(0);
    asm volatile("s_waitcnt lgkmcnt(0)" ::: "memory");
    __builtin_amdgcn_s_barrier();
    __builtin_amdgcn_sched_barrier(0);
  }

  // ---------------- epilogue: bias+relu -> Hts (ALIASES dead A-dbuf) ----------------
  // D map: col=lane&15, row=(lane>>4)*4+reg. AsU fully dead after GEMM1's final barrier.
  unsigned short (*Hts)[32][136] = reinterpret_cast<unsigned short (*)[32][136]>(AsU);
#pragma unroll
  for (int ht = 0; ht < 8; ++ht) {
    const float bias = gb1[16 * ht + r];                 // direct from L2 (epilogue, once)
#pragma unroll
    for (int reg = 0; reg < 4; ++reg) {
      Hts[w][4 * kg + reg][16 * ht + r]      = f2bf(fmaxf(acc0[ht][reg] + bias, 0.f));
      Hts[w][16 + 4 * kg + reg][16 * ht + r] = f2bf(fmaxf(acc1[ht][reg] + bias, 0.f));
    }
  }
  // wave-local write->read: per-wave DS ordering, no barrier needed
  short8 af0[4], af1[4];
#pragma unroll
  for (int kk = 0; kk < 4; ++kk) {
    af0[kk] = *reinterpret_cast<const short8*>(&Hts[w][r][32 * kk + 8 * kg]);
    af1[kk] = *reinterpret_cast<const short8*>(&Hts[w][16 + r][32 * kk + 8 * kg]);
  }
  // gsum_s aliases AsU bytes 34816..36864 (disjoint from Hts 0..34816 and B-dbuf 0..32768)
  float* gsum_s = reinterpret_cast<float*>(reinterpret_cast<char*>(AsU) + 34816);
  for (int i = t; i < NC; i += 256) gsum_s[i] = 0.f;
  // barrier: all af reads + gsum init retired before anyone writes the B-dbuf over Hts
  asm volatile("s_waitcnt lgkmcnt(0)" ::: "memory");
  __builtin_amdgcn_s_barrier();

  // ---------------- GEMM2: gsum[c] += sigmoid(H^T . gw2[c] + gb2), B dbuf in AsU ----------------
  unsigned short* Bs2 = reinterpret_cast<unsigned short*>(AsU);
  const int crow = lane >> 4;    // B2: row offset 0..3
  const int bs2  = lane & 15;    // B2: slot 0..15
  short8 bv[4];

#define LOADB2(ccn) { \
    _Pragma("unroll") \
    for (int j = 0; j < 4; ++j) { \
      const int cl = 16 * w + 4 * j + crow; \
      bv[j] = *reinterpret_cast<const short8*>(gw2b + (size_t)((ccn) * 64 + cl) * NH + bs2 * 8); \
    } }
#define WRITEB2(ccn) { \
    unsigned short* dstb = Bs2 + ((ccn) & 1) * 8192; \
    _Pragma("unroll") \
    for (int j = 0; j < 4; ++j) { \
      const int cl = 16 * w + 4 * j + crow; \
      *reinterpret_cast<short8*>(&dstb[cl * 128 + ((bs2 ^ (cl & 7)) * 8)]) = bv[j]; \
    } }

  LOADB2(0)
  WRITEB2(0)                      // safe: behind the af-protection barrier
  __syncthreads();
  for (int cc = 0; cc < 8; ++cc) {
    // bias loads FIRST (older than the LOADB2 prefetch -> waits never drain it)
    float gb2v[4];
#pragma unroll
    for (int ctt = 0; ctt < 4; ++ctt) gb2v[ctt] = gb2[cc * 64 + 16 * ctt + r];
    if (cc < 7) LOADB2(cc + 1)
    const unsigned short* Bbuf = Bs2 + (cc & 1) * 8192;
#pragma unroll
    for (int ctt = 0; ctt < 4; ++ctt) {
      f32x4 z0 = (f32x4){0.f,0.f,0.f,0.f}, z1 = (f32x4){0.f,0.f,0.f,0.f};
#pragma unroll
      for (int kk = 0; kk < 4; ++kk) {
        const short8 bf = *reinterpret_cast<const short8*>(
            &Bbuf[(16 * ctt + r) * 128 + (((4 * kk + kg) ^ (r & 7)) * 8)]);
        z0 = __builtin_amdgcn_mfma_f32_16x16x32_bf16(af0[kk], bf, z0, 0, 0, 0);
        z1 = __builtin_amdgcn_mfma_f32_16x16x32_bf16(af1[kk], bf, z1, 0, 0, 0);
      }
      const float bias = gb2v[ctt];
      float s = 0.f;
#pragma unroll
      for (int reg = 0; reg < 4; ++reg) {
        s += 1.f / (1.f + __expf(-(z0[reg] + bias)));
        s += 1.f / (1.f + __expf(-(z1[reg] + bias)));
      }
      s += __shfl_xor(s, 16);
      s += __shfl_xor(s, 32);
      if (lane < 16) atomicAdd(&gsum_s[cc * 64 + 16 * ctt + lane], s);
    }
    if (cc < 7) WRITEB2(cc + 1)
    __syncthreads();
  }
  for (int i = t; i < NC; i += 256) {
    atomicAdd(&gsum_g[b * NC + i], gsum_s[i]);
    atomicAdd(&csum_g[b * NC + i], csum_s[i]);
  }
}

// ---------------- K3: finalize stats + affine MLP -> per-(b,c) y = A*x + D ----------------
__global__ __launch_bounds__(256) void k3_final(
    const float* __restrict__ xsum, const float* __restrict__ xsumsq,
    const float* __restrict__ csum, const float* __restrict__ gsum,
    const float* __restrict__ mw1, const float* __restrict__ mb1,
    const float* __restrict__ mw2, const float* __restrict__ mb2,
    float* __restrict__ a_arr, float* __restrict__ d_arr) {
  __shared__ __align__(16) float cp[NC];
  __shared__ __align__(16) float hm[NH];
  __shared__ float gbv[2 * NC];
  __shared__ double red[8];
  __shared__ float mu_l_s, sig_l_s;
  const int b = blockIdx.x, t = threadIdx.x;

  double s1 = 0.0, s2 = 0.0;
  for (int c = t; c < NC; c += 256) { s1 += (double)xsum[b * NC + c]; s2 += (double)xsumsq[b * NC + c]; }
  for (int off = 32; off; off >>= 1) { s1 += __shfl_down(s1, off); s2 += __shfl_down(s2, off); }
  if ((t & 63) == 0) { red[(t >> 6) * 2] = s1; red[(t >> 6) * 2 + 1] = s2; }
  for (int c = t; c < NC; c += 256) cp[c] = csum[b * NC + c] * (1.f / NL);
  __syncthreads();
  if (t == 0) {
    double S1 = red[0] + red[2] + red[4] + red[6];
    double S2 = red[1] + red[3] + red[5] + red[7];
    double n = (double)NC * NL;
    double mu = S1 / n;
    double var = S2 / n - mu * mu;
    mu_l_s = (float)mu;
    sig_l_s = (float)sqrt(var + (double)FEPS);
  }
  __syncthreads();
  if (t < NH) {
    const float4* row = reinterpret_cast<const float4*>(mw1 + (size_t)t * NC);
    const float4* cpv = reinterpret_cast<const float4*>(cp);
    float acc = mb1[t];
    for (int i = 0; i < NC / 4; ++i) {
      float4 wv = row[i], xv = cpv[i];
      acc += wv.x * xv.x + wv.y * xv.y + wv.z * xv.z + wv.w * xv.w;
    }
    hm[t] = fmaxf(acc, 0.f);
  }
  __syncthreads();
  for (int o = t; o < 2 * NC; o += 256) {
    const float4* row = reinterpret_cast<const float4*>(mw2 + (size_t)o * NH);
    const float4* hv = reinterpret_cast<const float4*>(hm);
    float acc = mb2[o];
    for (int i = 0; i < NH / 4; ++i) {
      float4 wv = row[i], xv = hv[i];
      acc += wv.x * xv.x + wv.y * xv.y + wv.z * xv.z + wv.w * xv.w;
    }
    gbv[o] = acc;
  }
  __syncthreads();
  const float mu_l = mu_l_s, sig_l = sig_l_s;
  for (int c = t; c < NC; c += 256) {
    float gm = gsum[b * NC + c] * (1.f / NL);
    double mu_c = (double)xsum[b * NC + c] / NL;
    double var_c = (double)xsumsq[b * NC + c] / NL - mu_c * mu_c;
    float sig_c = (float)sqrt(var_c + (double)FEPS);
    float mu = gm * (float)mu_c + (1.f - gm) * mu_l;
    float sg = gm * sig_c + (1.f - gm) * sig_l;
    float gamma = gbv[c], beta = gbv[NC + c];
    float A = (1.f + gamma) / sg;
    a_arr[b * NC + c] = A;
    d_arr[b * NC + c] = beta - A * mu;
  }
}

// ---------------- K4: y = A*x + D, CACHED x reads (L3-warm from k12), nt y stores, imp = sum |y| ----------------
__global__ __launch_bounds__(256) void k4_y(
    const float* __restrict__ x, const float* __restrict__ a_arr,
    const float* __restrict__ d_arr, float* __restrict__ out, float* __restrict__ imp) {
  const int bc = blockIdx.x, t = threadIdx.x;
  const float A = a_arr[bc], D = d_arr[bc];
  const f32x4* xp = reinterpret_cast<const f32x4*>(x + (size_t)bc * NL);
  f32x4* op = reinterpret_cast<f32x4*>(out + (size_t)bc * NL);
  float s = 0.f;
#pragma unroll
  for (int i = 0; i < 8; ++i) {
    f32x4 v = xp[i * 256 + t];            // CACHED: x is L3-resident from k12's x-path
    f32x4 y;
    y.x = fmaf(A, v.x, D); y.y = fmaf(A, v.y, D);
    y.z = fmaf(A, v.z, D); y.w = fmaf(A, v.w, D);
    s += fabsf(y.x) + fabsf(y.y) + fabsf(y.z) + fabsf(y.w);
    __builtin_nontemporal_store(y, op + i * 256 + t);         // out never re-read
  }
  for (int off = 32; off; off >>= 1) s += __shfl_down(s, off);
  __shared__ float rs[4];
  if ((t & 63) == 0) rs[t >> 6] = s;
  __syncthreads();
  if (t == 0) imp[bc] = rs[0] + rs[1] + rs[2] + rs[3];
}

// ---------------- K5: fused top-k rank (jax.lax.top_k tie semantics) + zero dropped rows ----------------
__global__ __launch_bounds__(256) void k5_apply(
    const float* __restrict__ imp, float* __restrict__ out) {
  const int bc = blockIdx.x;
  const int b = bc >> 9;            // NC = 512
  const int c = bc & (NC - 1);
  const int t = threadIdx.x;
  const float* row = imp + b * NC;
  const float mine = row[c];
  int cnt = 0;
#pragma unroll
  for (int jj = 0; jj < 2; ++jj) {
    const int j = jj * 256 + t;
    const float o = row[j];
    cnt += (o > mine) || (o == mine && j < c);
  }
  for (int off = 32; off; off >>= 1) cnt += __shfl_down(cnt, off);
  __shared__ int rs[4];
  if ((t & 63) == 0) rs[t >> 6] = cnt;
  __syncthreads();
  const int rank = rs[0] + rs[1] + rs[2] + rs[3];   // block-uniform
  if (rank < NKEEP) return;
  f32x4* op = reinterpret_cast<f32x4*>(out + (size_t)bc * NL);
  const f32x4 z = (f32x4){0.f, 0.f, 0.f, 0.f};
#pragma unroll
  for (int i = 0; i < 8; ++i) __builtin_nontemporal_store(z, op + i * 256 + t);
}

extern "C" void kernel_launch(void* const* d_in, const int* in_sizes, int n_in,
                              void* d_out, int out_size, void* d_ws, size_t ws_size,
                              hipStream_t stream) {
  const float* x   = (const float*)d_in[0];
  const float* c   = (const float*)d_in[1];
  const float* gw1 = (const float*)d_in[2];
  const float* gb1 = (const float*)d_in[3];
  const float* gw2 = (const float*)d_in[4];
  const float* gb2 = (const float*)d_in[5];
  const float* mw1 = (const float*)d_in[6];
  const float* mb1 = (const float*)d_in[7];
  const float* mw2 = (const float*)d_in[8];
  const float* mb2 = (const float*)d_in[9];
  float* out = (float*)d_out;
  char* ws = (char*)d_ws;

  unsigned short* gw1b = (unsigned short*)(ws);             // 131072 B
  unsigned short* gw2b = (unsigned short*)(ws + 131072);    // 131072 B
  float* xsum   = (float*)(ws + 262144);
  float* xsumsq = (float*)(ws + 278528);
  float* csum   = (float*)(ws + 294912);
  float* gsum   = (float*)(ws + 311296);
  float* a_arr  = (float*)(ws + 327680);
  float* d_arr  = (float*)(ws + 344064);
  float* imp    = (float*)(ws + 360448);

  k0_prep<<<256, 256, 0, stream>>>(gw1, gw2, gw1b, gw2b, csum, gsum);
  k12_gate_x<<<512 + NB * NC, 256, 0, stream>>>(c, x, gw1b, gw2b, gb1, gb2,
                                                gsum, csum, xsum, xsumsq);
  k3_final<<<NB, 256, 0, stream>>>(xsum, xsumsq, csum, gsum, mw1, mb1, mw2, mb2, a_arr, d_arr);
  k4_y<<<NB * NC, 256, 0, stream>>>(x, a_arr, d_arr, out, imp);
  k5_apply<<<NB * NC, 256, 0, stream>>>(imp, out);
}